// Round 1
// baseline (29462.469 us; speedup 1.0000x reference)
//
#include <hip/hip_runtime.h>
#include <hip/hip_bf16.h>

#define TT 2048
#define BB 32
#define DD 256
#define HH 512
#define NWG 32      // workgroups per layer
#define UPW 16      // hidden units per workgroup

using f32x4 = __attribute__((ext_vector_type(4))) float;
using s16x8 = __attribute__((ext_vector_type(8))) short;

// Persistent state in static device memory (no d_ws dependence).
__device__ __attribute__((aligned(16))) __hip_bfloat16 g_h0[TT + 1][BB][HH];
__device__ __attribute__((aligned(16))) __hip_bfloat16 g_h1[TT + 1][BB][HH];
__device__ __attribute__((aligned(16))) float g_h1f[BB][HH];
__device__ int g_flag0[TT + 1][NWG];
__device__ int g_flag1[TT + 1][NWG];

__device__ __forceinline__ short f2bf(float f) {
    union { float f; unsigned u; } v; v.f = f;
    unsigned r = v.u + 0x7fffu + ((v.u >> 16) & 1u);  // RNE
    return (short)(r >> 16);
}
__device__ __forceinline__ float sigm(float x) { return 1.f / (1.f + __expf(-x)); }
__device__ __forceinline__ float tanh_f(float x) { return 1.f - 2.f / (__expf(2.f * x) + 1.f); }

// ---------------------------------------------------------------------------
// Persistent per-layer scan. wave = (m-tile, K-quarter); weights in VGPRs.
// ---------------------------------------------------------------------------
template <int LAYER>
__device__ void scan_layer(char* smem, int wgk,
                           const float* __restrict__ Wih, const float* __restrict__ Whh,
                           const float* __restrict__ bih, const float* __restrict__ bhh,
                           const float* __restrict__ x) {
    constexpr int KIN = (LAYER == 0) ? DD : HH;  // 256 / 512
    constexpr int KL  = KIN + HH;                // 768 / 1024
    constexpr int QK  = KL / 4;                  // 192 / 256 (K per wave-quarter)
    constexpr int NKQ = QK / 32;                 // 6 / 8 MFMA k-steps per quarter
    constexpr int NGR = KL / 128;                // 6 / 8 stage groups per thread
    constexpr int ROWB = 2048;                   // LDS A row stride (bytes)

    const int tid  = threadIdx.x;
    const int wave = tid >> 6;
    const int lane = tid & 63;
    const int m    = wave & 1;   // M tile (batch 16-half)
    const int q    = wave >> 1;  // K quarter
    const int u16  = lane & 15;
    const int hi   = lane >> 4;

    // ---- Load weight fragments into registers (one-time) ------------------
    s16x8 wreg[NKQ * 4];
    {
        const int unit = wgk * UPW + u16;
#pragma unroll
        for (int ks = 0; ks < NKQ; ++ks) {
#pragma unroll
            for (int gt = 0; gt < 4; ++gt) {
                const int k = q * QK + ks * 32 + hi * 8;
                const float* src = (k < KIN)
                    ? (Wih + (size_t)(gt * HH + unit) * KIN + k)
                    : (Whh + (size_t)(gt * HH + unit) * HH + (k - KIN));
                s16x8 w;
#pragma unroll
                for (int j = 0; j < 8; ++j) w[j] = f2bf(src[j]);
                wreg[ks * 4 + gt] = w;
            }
        }
    }

    // ---- Elementwise thread mapping: (batch, unit) owned per thread --------
    const int eb = tid >> 4;
    const int eu = tid & 15;
    const int unit_g = wgk * UPW + eu;
    float bias[4];
#pragma unroll
    for (int gt = 0; gt < 4; ++gt)
        bias[gt] = bih[gt * HH + unit_g] + bhh[gt * HH + unit_g];
    float c = 0.f;

    float* gbuf = (float*)smem;  // overlays A region (guarded by barriers)

    for (int t = 0; t < TT; ++t) {
        // ---- 1. Poll readiness flags (wave 0 only) -------------------------
        if (wave == 0) {
            int iters = 0;
            for (;;) {
                int v;
                if (LAYER == 0) {
                    v = (lane < NWG)
                        ? __hip_atomic_load(&g_flag0[t][lane], __ATOMIC_RELAXED, __HIP_MEMORY_SCOPE_AGENT)
                        : 1;
                } else {
                    v = (lane < NWG)
                        ? __hip_atomic_load(&g_flag0[t + 1][lane], __ATOMIC_RELAXED, __HIP_MEMORY_SCOPE_AGENT)
                        : __hip_atomic_load(&g_flag1[t][lane - NWG], __ATOMIC_RELAXED, __HIP_MEMORY_SCOPE_AGENT);
                }
                if (__all(v != 0)) break;
                if (++iters > (1 << 22)) break;  // convert potential hang -> wrong answer
                __builtin_amdgcn_s_sleep(1);
            }
            __builtin_amdgcn_fence(__ATOMIC_ACQUIRE, "agent");
        }
        __syncthreads();

        // ---- 2. Stage A = [x_t | h_prev] (L0) or [h0_t | h1_prev] (L1) -----
        {
            const int b = tid >> 4;
#pragma unroll
            for (int g = 0; g < NGR; ++g) {
                const int kg = (tid & 15) + 16 * g;
                const int k  = kg * 8;
                s16x8 v;
                if (LAYER == 0) {
                    if (k < KIN) {
                        const float* xs = x + ((size_t)b * TT + t) * DD + k;
                        const float4 x0 = *(const float4*)xs;
                        const float4 x1 = *(const float4*)(xs + 4);
                        v[0] = f2bf(x0.x); v[1] = f2bf(x0.y); v[2] = f2bf(x0.z); v[3] = f2bf(x0.w);
                        v[4] = f2bf(x1.x); v[5] = f2bf(x1.y); v[6] = f2bf(x1.z); v[7] = f2bf(x1.w);
                    } else {
                        v = *(const s16x8*)(&g_h0[t][b][k - KIN]);
                    }
                } else {
                    if (k < KIN) v = *(const s16x8*)(&g_h0[t + 1][b][k]);
                    else         v = *(const s16x8*)(&g_h1[t][b][k - KIN]);
                }
                const int off = kg * 16;
                *(s16x8*)(smem + b * ROWB + (off ^ ((b & 7) << 4))) = v;
            }
        }
        __syncthreads();

        // ---- 3. MFMA: 4 gate tiles per wave, A read once per k-step --------
        f32x4 acc[4] = {{0,0,0,0},{0,0,0,0},{0,0,0,0},{0,0,0,0}};
        {
            const int arow = m * 16 + u16;
            const char* abase = smem + arow * ROWB;
            const int aswz = (arow & 7) << 4;
#pragma unroll
            for (int ks = 0; ks < NKQ; ++ks) {
                const int off = (q * QK + ks * 32 + hi * 8) * 2;
                s16x8 a = *(const s16x8*)(abase + (off ^ aswz));
#pragma unroll
                for (int gt = 0; gt < 4; ++gt)
                    acc[gt] = __builtin_amdgcn_mfma_f32_16x16x32_bf16(a, wreg[ks * 4 + gt], acc[gt], 0, 0, 0);
            }
        }
        __syncthreads();  // A region dead; gbuf overlay now safe

        // ---- 4. Write K-quarter partials to LDS ----------------------------
#pragma unroll
        for (int gt = 0; gt < 4; ++gt) {
#pragma unroll
            for (int r = 0; r < 4; ++r) {
                const int b = m * 16 + hi * 4 + r;  // C row = (lane>>4)*4 + reg
                gbuf[(q * BB + b) * 68 + gt * 16 + u16] = acc[gt][r];
            }
        }
        __syncthreads();

        // ---- 5. Gate elementwise + publish h -------------------------------
        {
            float gv[4];
#pragma unroll
            for (int gt = 0; gt < 4; ++gt) {
                float s = bias[gt];
#pragma unroll
                for (int qq = 0; qq < 4; ++qq) s += gbuf[(qq * BB + eb) * 68 + gt * 16 + eu];
                gv[gt] = s;
            }
            const float ig = sigm(gv[0]);
            const float fg = sigm(gv[1]);
            const float gg = tanh_f(gv[2]);
            const float og = sigm(gv[3]);
            c = fg * c + ig * gg;
            const float h = og * tanh_f(c);
            const unsigned short hu = (unsigned short)f2bf(h);
            if (LAYER == 0) {
                *(unsigned short*)&g_h0[t + 1][eb][unit_g] = hu;
            } else {
                *(unsigned short*)&g_h1[t + 1][eb][unit_g] = hu;
                if (t == TT - 1) g_h1f[eb][unit_g] = h;
            }
        }
        __threadfence();   // agent-scope: flush to coherence point (cross-XCD)
        __syncthreads();
        if (tid == 0) {
            if (LAYER == 0)
                __hip_atomic_store(&g_flag0[t + 1][wgk], 1, __ATOMIC_RELEASE, __HIP_MEMORY_SCOPE_AGENT);
            else
                __hip_atomic_store(&g_flag1[t + 1][wgk], 1, __ATOMIC_RELEASE, __HIP_MEMORY_SCOPE_AGENT);
        }
    }
}

__global__ __launch_bounds__(512, 2) void lstm_scan(
    const float* __restrict__ x,
    const float* __restrict__ Wih0, const float* __restrict__ Whh0,
    const float* __restrict__ bih0, const float* __restrict__ bhh0,
    const float* __restrict__ Wih1, const float* __restrict__ Whh1,
    const float* __restrict__ bih1, const float* __restrict__ bhh1) {
    __shared__ __attribute__((aligned(16))) char smem[65536];
    const int layer = blockIdx.x >> 5;
    const int wgk   = blockIdx.x & (NWG - 1);
    if (layer == 0) scan_layer<0>(smem, wgk, Wih0, Whh0, bih0, bhh0, x);
    else            scan_layer<1>(smem, wgk, Wih1, Whh1, bih1, bhh1, nullptr);
}

__global__ void reset_kernel() {
    const int n = (TT + 1) * NWG;
    int* f0 = &g_flag0[0][0];
    int* f1 = &g_flag1[0][0];
    for (int i = blockIdx.x * blockDim.x + threadIdx.x; i < n; i += gridDim.x * blockDim.x) {
        const int v = (i < NWG) ? 1 : 0;  // slot 0 (zero initial state) pre-ready
        f0[i] = v;
        f1[i] = v;
    }
    unsigned short* h0 = (unsigned short*)&g_h0[0][0][0];
    unsigned short* h1 = (unsigned short*)&g_h1[0][0][0];
    for (int i = blockIdx.x * blockDim.x + threadIdx.x; i < BB * HH; i += gridDim.x * blockDim.x) {
        h0[i] = 0;
        h1[i] = 0;
    }
}

__global__ void out_kernel(const float* __restrict__ Wout, const float* __restrict__ bout,
                           float* __restrict__ out) {
    const int b = blockIdx.x;
    const int o = threadIdx.x;
    const float* h = &g_h1f[b][0];
    const float* w = Wout + (size_t)o * HH;
    float s = bout[o];
    for (int k = 0; k < HH; k += 4)
        s += h[k] * w[k] + h[k + 1] * w[k + 1] + h[k + 2] * w[k + 2] + h[k + 3] * w[k + 3];
    out[b * 256 + o] = s;
}

extern "C" void kernel_launch(void* const* d_in, const int* in_sizes, int n_in,
                              void* d_out, int out_size, void* d_ws, size_t ws_size,
                              hipStream_t stream) {
    const float* x    = (const float*)d_in[0];
    const float* Wih0 = (const float*)d_in[1];
    const float* Whh0 = (const float*)d_in[2];
    const float* bih0 = (const float*)d_in[3];
    const float* bhh0 = (const float*)d_in[4];
    const float* Wih1 = (const float*)d_in[5];
    const float* Whh1 = (const float*)d_in[6];
    const float* bih1 = (const float*)d_in[7];
    const float* bhh1 = (const float*)d_in[8];
    const float* Wout = (const float*)d_in[9];
    const float* bout = (const float*)d_in[10];
    float* out = (float*)d_out;

    hipLaunchKernelGGL(reset_kernel, dim3(128), dim3(256), 0, stream);
    hipLaunchKernelGGL(lstm_scan, dim3(2 * NWG), dim3(512), 0, stream,
                       x, Wih0, Whh0, bih0, bhh0, Wih1, Whh1, bih1, bhh1);
    hipLaunchKernelGGL(out_kernel, dim3(BB), dim3(256), 0, stream, Wout, bout, out);
}

// Round 2
// 11198.388 us; speedup vs baseline: 2.6310x; 2.6310x over previous
//
#include <hip/hip_runtime.h>
#include <hip/hip_bf16.h>

#define TT 2048
#define BB 32
#define DD 256
#define HH 512
#define NWG 32      // workgroups per layer
#define UPW 16      // hidden units per workgroup

using f32x4 = __attribute__((ext_vector_type(4))) float;
using s16x8 = __attribute__((ext_vector_type(8))) short;

// Persistent state in static device memory (no d_ws dependence).
__device__ __attribute__((aligned(16))) __hip_bfloat16 g_h0[TT + 1][BB][HH];
__device__ __attribute__((aligned(16))) __hip_bfloat16 g_h1[TT + 1][BB][HH];
__device__ __attribute__((aligned(16))) float g_h1f[BB][HH];
__device__ int g_flag0[TT + 1][NWG];
__device__ int g_flag1[TT + 1][NWG];

__device__ __forceinline__ short f2bf(float f) {
    union { float f; unsigned u; } v; v.f = f;
    unsigned r = v.u + 0x7fffu + ((v.u >> 16) & 1u);  // RNE
    return (short)(r >> 16);
}
__device__ __forceinline__ float sigm(float x) { return 1.f / (1.f + __expf(-x)); }
__device__ __forceinline__ float tanh_f(float x) { return 1.f - 2.f / (__expf(2.f * x) + 1.f); }

// 16B device-coherent load (2x 8B agent-scope relaxed atomics -> sc1, bypasses L1/L2)
__device__ __forceinline__ s16x8 aload16(const __hip_bfloat16* p) {
    const unsigned long long* q = (const unsigned long long*)p;
    union { unsigned long long u[2]; s16x8 v; } r;
    r.u[0] = __hip_atomic_load(q,     __ATOMIC_RELAXED, __HIP_MEMORY_SCOPE_AGENT);
    r.u[1] = __hip_atomic_load(q + 1, __ATOMIC_RELAXED, __HIP_MEMORY_SCOPE_AGENT);
    return r.v;
}

// ---------------------------------------------------------------------------
// Persistent per-layer scan. wave = (m-tile, K-quarter); weights in VGPRs.
// Cross-wg sync: sc1 write-through publishes + relaxed-atomic polls.
// NO agent fences in the step loop (buffer_wbl2 / buffer_inv were the
// round-1 bottleneck: 14.4 us/step, 12x HBM over-fetch).
// ---------------------------------------------------------------------------
template <int LAYER>
__device__ void scan_layer(char* smem, int wgk,
                           const float* __restrict__ Wih, const float* __restrict__ Whh,
                           const float* __restrict__ bih, const float* __restrict__ bhh,
                           const float* __restrict__ x) {
    constexpr int KIN = (LAYER == 0) ? DD : HH;  // 256 / 512
    constexpr int KL  = KIN + HH;                // 768 / 1024
    constexpr int QK  = KL / 4;                  // 192 / 256 (K per wave-quarter)
    constexpr int NKQ = QK / 32;                 // 6 / 8 MFMA k-steps per quarter
    constexpr int NGR = KL / 128;                // 6 / 8 stage groups per thread
    constexpr int ROWB = 2048;                   // LDS A row stride (bytes)

    const int tid  = threadIdx.x;
    const int wave = tid >> 6;
    const int lane = tid & 63;
    const int m    = wave & 1;   // M tile (batch 16-half)
    const int q    = wave >> 1;  // K quarter
    const int u16  = lane & 15;
    const int hi   = lane >> 4;

    // ---- Load weight fragments into registers (one-time) ------------------
    s16x8 wreg[NKQ * 4];
    {
        const int unit = wgk * UPW + u16;
#pragma unroll
        for (int ks = 0; ks < NKQ; ++ks) {
#pragma unroll
            for (int gt = 0; gt < 4; ++gt) {
                const int k = q * QK + ks * 32 + hi * 8;
                const float* src = (k < KIN)
                    ? (Wih + (size_t)(gt * HH + unit) * KIN + k)
                    : (Whh + (size_t)(gt * HH + unit) * HH + (k - KIN));
                s16x8 w;
#pragma unroll
                for (int j = 0; j < 8; ++j) w[j] = f2bf(src[j]);
                wreg[ks * 4 + gt] = w;
            }
        }
    }

    // ---- Elementwise thread mapping: (batch, unit) owned per thread --------
    const int eb = tid >> 4;
    const int eu = tid & 15;
    const int unit_g = wgk * UPW + eu;
    float bias[4];
#pragma unroll
    for (int gt = 0; gt < 4; ++gt)
        bias[gt] = bih[gt * HH + unit_g] + bhh[gt * HH + unit_g];
    float c = 0.f;

    float* gbuf = (float*)smem;  // overlays A region (guarded by barriers)

    for (int t = 0; t < TT; ++t) {
        // ---- 0. Prefetch flag-independent x fragments (L0 only) -----------
        s16x8 xpre[2];
        if (LAYER == 0) {
            const int b = tid >> 4;
#pragma unroll
            for (int g = 0; g < 2; ++g) {
                const int k = ((tid & 15) + 16 * g) * 8;
                const float* xs = x + ((size_t)b * TT + t) * DD + k;
                const float4 x0 = *(const float4*)xs;
                const float4 x1 = *(const float4*)(xs + 4);
                s16x8 v;
                v[0] = f2bf(x0.x); v[1] = f2bf(x0.y); v[2] = f2bf(x0.z); v[3] = f2bf(x0.w);
                v[4] = f2bf(x1.x); v[5] = f2bf(x1.y); v[6] = f2bf(x1.z); v[7] = f2bf(x1.w);
                xpre[g] = v;
            }
        }

        // ---- 1. Poll readiness flags (wave 0), tight, no fences ------------
        if (wave == 0) {
            int iters = 0;
            for (;;) {
                int v;
                if (LAYER == 0) {
                    v = (lane < NWG)
                        ? __hip_atomic_load(&g_flag0[t][lane], __ATOMIC_RELAXED, __HIP_MEMORY_SCOPE_AGENT)
                        : 1;
                } else {
                    v = (lane < NWG)
                        ? __hip_atomic_load(&g_flag0[t + 1][lane], __ATOMIC_RELAXED, __HIP_MEMORY_SCOPE_AGENT)
                        : __hip_atomic_load(&g_flag1[t][lane - NWG], __ATOMIC_RELAXED, __HIP_MEMORY_SCOPE_AGENT);
                }
                if (__all(v != 0)) break;
                if (++iters > (1 << 22)) break;  // convert potential hang -> wrong answer
            }
        }
        __syncthreads();

        // ---- 2. Stage A = [x_t | h_prev] (L0) or [h0_t | h1_prev] (L1) -----
        {
            const int b = tid >> 4;
#pragma unroll
            for (int g = 0; g < NGR; ++g) {
                const int kg = (tid & 15) + 16 * g;
                const int k  = kg * 8;
                s16x8 v;
                if (LAYER == 0) {
                    if (g < 2) v = xpre[g];                              // x (k < 256)
                    else       v = aload16(&g_h0[t][b][k - KIN]);        // h0[t]
                } else {
                    if (g < 4) v = aload16(&g_h0[t + 1][b][k]);          // h0[t+1]
                    else       v = aload16(&g_h1[t][b][k - KIN]);        // h1[t]
                }
                const int off = kg * 16;
                *(s16x8*)(smem + b * ROWB + (off ^ ((b & 7) << 4))) = v;
            }
        }
        __syncthreads();

        // ---- 3. MFMA: 4 gate tiles per wave, A read once per k-step --------
        f32x4 acc[4] = {{0,0,0,0},{0,0,0,0},{0,0,0,0},{0,0,0,0}};
        {
            const int arow = m * 16 + u16;
            const char* abase = smem + arow * ROWB;
            const int aswz = (arow & 7) << 4;
#pragma unroll
            for (int ks = 0; ks < NKQ; ++ks) {
                const int off = (q * QK + ks * 32 + hi * 8) * 2;
                s16x8 a = *(const s16x8*)(abase + (off ^ aswz));
#pragma unroll
                for (int gt = 0; gt < 4; ++gt)
                    acc[gt] = __builtin_amdgcn_mfma_f32_16x16x32_bf16(a, wreg[ks * 4 + gt], acc[gt], 0, 0, 0);
            }
        }
        __syncthreads();  // A region dead; gbuf overlay now safe

        // ---- 4. Write K-quarter partials to LDS ----------------------------
#pragma unroll
        for (int gt = 0; gt < 4; ++gt) {
#pragma unroll
            for (int r = 0; r < 4; ++r) {
                const int b = m * 16 + hi * 4 + r;  // C row = (lane>>4)*4 + reg
                gbuf[(q * BB + b) * 68 + gt * 16 + u16] = acc[gt][r];
            }
        }
        __syncthreads();

        // ---- 5. Gate elementwise + publish h (sc1 write-through) -----------
        {
            float gv[4];
#pragma unroll
            for (int gt = 0; gt < 4; ++gt) {
                float s = bias[gt];
#pragma unroll
                for (int qq = 0; qq < 4; ++qq) s += gbuf[(qq * BB + eb) * 68 + gt * 16 + eu];
                gv[gt] = s;
            }
            const float ig = sigm(gv[0]);
            const float fg = sigm(gv[1]);
            const float gg = tanh_f(gv[2]);
            const float og = sigm(gv[3]);
            c = fg * c + ig * gg;
            const float h = og * tanh_f(c);
            const unsigned hu = (unsigned)(unsigned short)f2bf(h);
            const unsigned other = __shfl_xor(hu, 1);
            if (LAYER == 1 && t == TT - 1) g_h1f[eb][unit_g] = h;
            if ((eu & 1) == 0) {
                const unsigned packed = hu | (other << 16);
                unsigned* dst = (LAYER == 0)
                    ? (unsigned*)&g_h0[t + 1][eb][unit_g]
                    : (unsigned*)&g_h1[t + 1][eb][unit_g];
                __hip_atomic_store(dst, packed, __ATOMIC_RELAXED, __HIP_MEMORY_SCOPE_AGENT);
            }
        }
        // All sc1 stores ack at the coherence point before the flag goes out:
        asm volatile("s_waitcnt vmcnt(0)" ::: "memory");
        __syncthreads();
        if (tid == 0) {
            if (LAYER == 0)
                __hip_atomic_store(&g_flag0[t + 1][wgk], 1, __ATOMIC_RELAXED, __HIP_MEMORY_SCOPE_AGENT);
            else
                __hip_atomic_store(&g_flag1[t + 1][wgk], 1, __ATOMIC_RELAXED, __HIP_MEMORY_SCOPE_AGENT);
        }
    }
}

__global__ __launch_bounds__(512, 2) void lstm_scan(
    const float* __restrict__ x,
    const float* __restrict__ Wih0, const float* __restrict__ Whh0,
    const float* __restrict__ bih0, const float* __restrict__ bhh0,
    const float* __restrict__ Wih1, const float* __restrict__ Whh1,
    const float* __restrict__ bih1, const float* __restrict__ bhh1) {
    __shared__ __attribute__((aligned(16))) char smem[65536];
    const int layer = blockIdx.x >> 5;
    const int wgk   = blockIdx.x & (NWG - 1);
    if (layer == 0) scan_layer<0>(smem, wgk, Wih0, Whh0, bih0, bhh0, x);
    else            scan_layer<1>(smem, wgk, Wih1, Whh1, bih1, bhh1, nullptr);
}

__global__ void reset_kernel() {
    const int n = (TT + 1) * NWG;
    int* f0 = &g_flag0[0][0];
    int* f1 = &g_flag1[0][0];
    for (int i = blockIdx.x * blockDim.x + threadIdx.x; i < n; i += gridDim.x * blockDim.x) {
        const int v = (i < NWG) ? 1 : 0;  // slot 0 (zero initial state) pre-ready
        f0[i] = v;
        f1[i] = v;
    }
    unsigned short* h0 = (unsigned short*)&g_h0[0][0][0];
    unsigned short* h1 = (unsigned short*)&g_h1[0][0][0];
    for (int i = blockIdx.x * blockDim.x + threadIdx.x; i < BB * HH; i += gridDim.x * blockDim.x) {
        h0[i] = 0;
        h1[i] = 0;
    }
}

__global__ void out_kernel(const float* __restrict__ Wout, const float* __restrict__ bout,
                           float* __restrict__ out) {
    const int b = blockIdx.x;
    const int o = threadIdx.x;
    const float4* h4 = (const float4*)&g_h1f[b][0];
    const float4* w4 = (const float4*)(Wout + (size_t)o * HH);
    float s = bout[o];
    for (int k = 0; k < HH / 4; ++k) {
        const float4 a = h4[k], w = w4[k];
        s += a.x * w.x + a.y * w.y + a.z * w.z + a.w * w.w;
    }
    out[b * 256 + o] = s;
}

extern "C" void kernel_launch(void* const* d_in, const int* in_sizes, int n_in,
                              void* d_out, int out_size, void* d_ws, size_t ws_size,
                              hipStream_t stream) {
    const float* x    = (const float*)d_in[0];
    const float* Wih0 = (const float*)d_in[1];
    const float* Whh0 = (const float*)d_in[2];
    const float* bih0 = (const float*)d_in[3];
    const float* bhh0 = (const float*)d_in[4];
    const float* Wih1 = (const float*)d_in[5];
    const float* Whh1 = (const float*)d_in[6];
    const float* bih1 = (const float*)d_in[7];
    const float* bhh1 = (const float*)d_in[8];
    const float* Wout = (const float*)d_in[9];
    const float* bout = (const float*)d_in[10];
    float* out = (float*)d_out;

    hipLaunchKernelGGL(reset_kernel, dim3(128), dim3(256), 0, stream);
    hipLaunchKernelGGL(lstm_scan, dim3(2 * NWG), dim3(512), 0, stream,
                       x, Wih0, Whh0, bih0, bhh0, Wih1, Whh1, bih1, bhh1);
    hipLaunchKernelGGL(out_kernel, dim3(BB), dim3(256), 0, stream, Wout, bout, out);
}